// Round 7
// baseline (242.488 us; speedup 1.0000x reference)
//
#include <hip/hip_runtime.h>

// Izhikevich neuron scan. x: [B=16, C=64, N=1024, T=32] f32, T contiguous.
// 1M neurons = 16384 tiles of (64 neurons x 32 timesteps) = 8 KB tiles.
//
// R6 post-mortem: six structures (R1-R6) all plateau at ~80 us / 2.5 TB/s
// while fillBuffer does 6.6 TB/s in the same capture. Root cause common to
// all: compiler-inserted s_waitcnt vmcnt(0) drains ALL outstanding loads
// before compute (register first-use or conservative LDS aliasing for
// global_load_lds), so waves compute with zero bytes in flight -> ~4 KB avg
// outstanding/CU -> ~4 B/cyc/CU (Little's law), exactly as measured.
//
// R7: AITER-style manual VMEM. All global loads/stores are inline asm —
// invisible to SIInsertWaitcnts, which therefore inserts no vmcnt for them.
// One manual s_waitcnt vmcnt(8) per iteration drains the CURRENT tile's
// loads + previous stores while leaving the NEXT tile's 8 loads in flight
// across the whole LDS+compute+store phase. Per-wave vmem program order:
// [8 loads nxt][wait vmcnt(8)][scatter/compute/readback][8 stores] ->
// outstanding peaks at 24, in-order FIFO drain (m135). Final iteration
// waits vmcnt(0) to protect store-data regs before reuse/endpgm.
// Compiler keeps handling lgkmcnt (DS FIFO is in-order; m97-quality).
//
// Single-wave blocks (no barriers), 8 KB wave-private LDS, R4's proven
// XOR-swizzle tile layout. Grid 4096 = 16 blocks/CU ~= residency.
//
// Numerics: bit-exact f32 replication of the numpy reference (contract off,
// left-assoc order, literal spike-blend). LDS round-trip preserves bits.

typedef float v4f __attribute__((ext_vector_type(4)));

#define TPB 64
#define ITERS 4

__global__ __launch_bounds__(TPB) void izhikevich_kernel(
    const float* __restrict__ x,
    const float* __restrict__ pa,
    const float* __restrict__ pb,
    const float* __restrict__ pc,
    const float* __restrict__ pd,
    float* __restrict__ out,
    int stride_tiles)
{
#pragma clang fp contract(off)
    __shared__ float L[2048];                   // 8 KB, wave-private

    const int lane = threadIdx.x;               // single-wave block
    const int oct  = lane >> 3;                 // 0..7
    const int grp  = lane & 7;                  // 0..7
    const int scat_base = oct * 32 + ((grp ^ oct) << 2);
    const int row_base  = lane * 32;

    const float a = pa[0];
    const float b = pb[0];
    const float c = pc[0];
    const float d = pd[0];
    // Force a..d materialized (and their loads waited) BEFORE the first asm
    // load, so no compiler vmcnt(0) for them lands inside the loop.
    asm volatile("" :: "v"(a), "v"(b), "v"(c), "v"(d));

    const int off0 = lane * 16;                 // byte voffset, chunks 0..3
    const int off4 = off0 + 4096;               // byte voffset, chunks 4..7

    const int wid = blockIdx.x;

    v4f A0, A1, A2, A3, A4, A5, A6, A7;         // reg buffer A
    v4f B0, B1, B2, B3, B4, B5, B6, B7;         // reg buffer B

// 8 coalesced dwordx4 loads of one 8 KB tile; no compiler-visible vmem.
#define LOAD8(basep, r0, r1, r2, r3, r4, r5, r6, r7)                        \
    asm volatile(                                                           \
        "global_load_dwordx4 %0, %8, %10 offset:0\n\t"                      \
        "global_load_dwordx4 %1, %8, %10 offset:1024\n\t"                   \
        "global_load_dwordx4 %2, %8, %10 offset:2048\n\t"                   \
        "global_load_dwordx4 %3, %8, %10 offset:3072\n\t"                   \
        "global_load_dwordx4 %4, %9, %10 offset:0\n\t"                      \
        "global_load_dwordx4 %5, %9, %10 offset:1024\n\t"                   \
        "global_load_dwordx4 %6, %9, %10 offset:2048\n\t"                   \
        "global_load_dwordx4 %7, %9, %10 offset:3072"                       \
        : "=&v"(r0), "=&v"(r1), "=&v"(r2), "=&v"(r3),                       \
          "=&v"(r4), "=&v"(r5), "=&v"(r6), "=&v"(r7)                        \
        : "v"(off0), "v"(off4), "s"(basep))

#define WAITVM(n) asm volatile("s_waitcnt vmcnt(" #n ")" ::: "memory")

// Scatter tile regs -> LDS (XOR swizzle), per-neuron recurrence, spikes back
// to LDS, transposed readback, 8 coalesced asm stores.
#define PROCESS(tile, r0, r1, r2, r3, r4, r5, r6, r7)                       \
    do {                                                                    \
        *reinterpret_cast<v4f*>(&L[0 * 256 + scat_base]) = r0;              \
        *reinterpret_cast<v4f*>(&L[1 * 256 + scat_base]) = r1;              \
        *reinterpret_cast<v4f*>(&L[2 * 256 + scat_base]) = r2;              \
        *reinterpret_cast<v4f*>(&L[3 * 256 + scat_base]) = r3;              \
        *reinterpret_cast<v4f*>(&L[4 * 256 + scat_base]) = r4;              \
        *reinterpret_cast<v4f*>(&L[5 * 256 + scat_base]) = r5;              \
        *reinterpret_cast<v4f*>(&L[6 * 256 + scat_base]) = r6;              \
        *reinterpret_cast<v4f*>(&L[7 * 256 + scat_base]) = r7;              \
        v4f xs[8];                                                          \
        _Pragma("unroll")                                                   \
        for (int q = 0; q < 8; ++q)                                         \
            xs[q] = *reinterpret_cast<const v4f*>(                          \
                &L[row_base + ((q ^ grp) << 2)]);                           \
        float* xf = reinterpret_cast<float*>(xs);                           \
        float v = 0.0f;                                                     \
        float u = 0.0f;                                                     \
        _Pragma("unroll")                                                   \
        for (int j = 0; j < 32; ++j) {                                      \
            const float xt = xf[j];                                         \
            const float t1 = (0.04f * v) * v;                               \
            const float t2 = 5.0f * v;                                      \
            const float dv = (((t1 + t2) + 140.0f) - u) + xt;               \
            v = v + dv;                         /* DT = 1.0 exact */        \
            const float du = a * ((b * v) - u);                             \
            u = u + du;                                                     \
            const float spike = (v >= 30.0f) ? 1.0f : 0.0f;                 \
            const float oms = 1.0f - spike;                                 \
            v = (v * oms) + (c * spike);        /* exact, spike in {0,1} */ \
            u = u + (d * spike);                                            \
            xf[j] = spike;                      /* in-place, saves VGPRs */ \
        }                                                                   \
        _Pragma("unroll")                                                   \
        for (int q = 0; q < 8; ++q)                                         \
            *reinterpret_cast<v4f*>(&L[row_base + ((q ^ grp) << 2)]) =      \
                xs[q];                                                      \
        v4f o0 = *reinterpret_cast<const v4f*>(&L[0 * 256 + scat_base]);    \
        v4f o1 = *reinterpret_cast<const v4f*>(&L[1 * 256 + scat_base]);    \
        v4f o2 = *reinterpret_cast<const v4f*>(&L[2 * 256 + scat_base]);    \
        v4f o3 = *reinterpret_cast<const v4f*>(&L[3 * 256 + scat_base]);    \
        v4f o4 = *reinterpret_cast<const v4f*>(&L[4 * 256 + scat_base]);    \
        v4f o5 = *reinterpret_cast<const v4f*>(&L[5 * 256 + scat_base]);    \
        v4f o6 = *reinterpret_cast<const v4f*>(&L[6 * 256 + scat_base]);    \
        v4f o7 = *reinterpret_cast<const v4f*>(&L[7 * 256 + scat_base]);    \
        const float* obase = out + (size_t)(tile) * 2048;                   \
        asm volatile(                                                       \
            "global_store_dwordx4 %8, %0, %10 offset:0\n\t"                 \
            "global_store_dwordx4 %8, %1, %10 offset:1024\n\t"              \
            "global_store_dwordx4 %8, %2, %10 offset:2048\n\t"              \
            "global_store_dwordx4 %8, %3, %10 offset:3072\n\t"              \
            "global_store_dwordx4 %9, %4, %10 offset:0\n\t"                 \
            "global_store_dwordx4 %9, %5, %10 offset:1024\n\t"              \
            "global_store_dwordx4 %9, %6, %10 offset:2048\n\t"              \
            "global_store_dwordx4 %9, %7, %10 offset:3072"                  \
            :                                                               \
            : "v"(o0), "v"(o1), "v"(o2), "v"(o3),                           \
              "v"(o4), "v"(o5), "v"(o6), "v"(o7),                           \
              "v"(off0), "v"(off4), "s"(obase)                              \
            : "memory");                                                    \
    } while (0)

    const int s1 = stride_tiles;
    // Prologue: tile 0 -> A.
    LOAD8(x + (size_t)wid * 2048, A0, A1, A2, A3, A4, A5, A6, A7);

    // i = 0: load tile 1 -> B, process tile 0 (A).
    LOAD8(x + (size_t)(wid + s1) * 2048, B0, B1, B2, B3, B4, B5, B6, B7);
    WAITVM(8);
    PROCESS(wid, A0, A1, A2, A3, A4, A5, A6, A7);

    // i = 1: load tile 2 -> A, process tile 1 (B).
    LOAD8(x + (size_t)(wid + 2 * s1) * 2048, A0, A1, A2, A3, A4, A5, A6, A7);
    WAITVM(8);
    PROCESS(wid + s1, B0, B1, B2, B3, B4, B5, B6, B7);

    // i = 2: load tile 3 -> B, process tile 2 (A).
    LOAD8(x + (size_t)(wid + 3 * s1) * 2048, B0, B1, B2, B3, B4, B5, B6, B7);
    WAITVM(8);
    PROCESS(wid + 2 * s1, A0, A1, A2, A3, A4, A5, A6, A7);

    // i = 3: process tile 3 (B). vmcnt(0): drain B's loads AND i=2's stores
    // (store-data reg protection) before the final PROCESS.
    WAITVM(0);
    PROCESS(wid + 3 * s1, B0, B1, B2, B3, B4, B5, B6, B7);

#undef LOAD8
#undef WAITVM
#undef PROCESS
}

extern "C" void kernel_launch(void* const* d_in, const int* in_sizes, int n_in,
                              void* d_out, int out_size, void* d_ws, size_t ws_size,
                              hipStream_t stream) {
    const float* x  = (const float*)d_in[0];
    const float* pa = (const float*)d_in[1];
    const float* pb = (const float*)d_in[2];
    const float* pc = (const float*)d_in[3];
    const float* pd = (const float*)d_in[4];
    float* out = (float*)d_out;

    const int n_neurons = in_sizes[0] / 32;        // 1,048,576
    const int n_tiles = n_neurons / 64;            // 16384
    const int grid = n_tiles / ITERS;              // 4096
    const int stride_tiles = grid;                 // 4096

    izhikevich_kernel<<<grid, TPB, 0, stream>>>(x, pa, pb, pc, pd, out,
                                                stride_tiles);
}